// Round 4
// baseline (720.104 us; speedup 1.0000x reference)
//
#include <hip/hip_runtime.h>

typedef unsigned short u16;
typedef unsigned int   u32;
typedef _Float16       f16;

#define M_DIM 4096
#define K_DIM 4096
#define N_DIM 11008
#define NQ8   (N_DIM / 8)
#define BM 128
#define BN 128
#define BK 32
#define BKA 40  // padded k-stride of As rows (halfs): 80B rows
#define BKP 40  // padded k-stride of Bs rows (halfs): 80B rows

typedef f16   f16x8 __attribute__((ext_vector_type(8)));
typedef float f32x4 __attribute__((ext_vector_type(4)));

__device__ __forceinline__ u32 pk2(float lo, float hi) {
    // v_cvt_pkrtz_f16_f32: D[15:0]=f16(lo), D[31:16]=f16(hi). RTZ; exact when
    // the value fits fp16 (x does; W's 16-bit mantissa rounds with err < 2^-11).
    return __builtin_bit_cast(u32, __builtin_amdgcn_cvt_pkrtz(lo, hi));
}

// C = x[M,K] @ dequant(qweight)[K,N].  x,scales,out are fp32 on device
// (harness promotes fp16 -> fp32).  Math done in fp16 MFMA / fp32 accum:
// W[k,n] = s[g,n] * (w - z - 1), g = k/128 (g_idx affine).
__global__ __launch_bounds__(256, 2)
void gptq_gemm(const float* __restrict__ x, const int* __restrict__ qw,
               const float* __restrict__ sc, const int* __restrict__ qz,
               float* __restrict__ out)
{
    __shared__ __align__(16) f16 As[BM * BKA];   // [m][k] 128 x 40 (32 used)
    __shared__ __align__(16) f16 Bs[BN * BKP];   // [n][k] 128 x 40 (32 used)

    const int tid  = threadIdx.x;
    const int lane = tid & 63;
    const int wave = tid >> 6;
    const int quad = lane >> 4;
    const int l15  = lane & 15;
    const int wm   = (wave & 1) * 64;
    const int wn   = (wave >> 1) * 64;

    const int m0 = blockIdx.y * BM;
    const int n0 = blockIdx.x * BN;

    // --- A staging: thread -> row tid/2, k-offset (tid&1)*16; 16 fp32 -> 16 f16 ---
    const float* ag = x + (size_t)(m0 + (tid >> 1)) * K_DIM + (tid & 1) * 16;
    f16* al = As + (tid >> 1) * BKA + (tid & 1) * 16;

    // --- B dequant params (fixed n per thread) ---
    const int dn  = tid & 127;
    const int dkq = tid >> 7;    // handles qweight rows dkq and dkq+2 of the k-tile
    const int gn  = n0 + dn;
    const int zsh = (gn & 7) * 4;
    const int*   qwp = qw + gn;
    const int*   qzp = qz + (gn >> 3);
    const float* scp = sc + gn;
    f16* bs0 = Bs + dn * BKP + dkq * 8;

    f32x4 acc[4][4];
    #pragma unroll
    for (int i = 0; i < 4; i++)
        #pragma unroll
        for (int j = 0; j < 4; j++)
            acc[i][j] = (f32x4){0.f, 0.f, 0.f, 0.f};

    for (int kt = 0; kt < K_DIM / BK; kt++) {
        // A: global fp32 -> regs
        const float4* agp = (const float4*)(ag + kt * BK);
        float4 a0 = agp[0], a1 = agp[1], a2 = agp[2], a3 = agp[3];

        // B: dequant 2 int32 (16 k-values) for this thread's n
        const int gi = kt >> 2;                       // quant group (BK=32 within one group)
        const u32 zq = (u32)qzp[(size_t)gi * NQ8];
        const int z1 = (int)((zq >> zsh) & 15u) + 1;
        const float s = scp[(size_t)gi * N_DIM];
        const float c = -s * (float)z1;               // val = s*w + c  (exact in fp32)
        uint4 bv[2];
        #pragma unroll
        for (int i = 0; i < 2; i++) {
            const u32 q = (u32)qwp[(size_t)(4 * kt + dkq + 2 * i) * N_DIM];
            u32 pk[4];
            #pragma unroll
            for (int jj = 0; jj < 4; jj++) {
                float f0 = fmaf((float)((q >> (8 * jj)) & 15u), s, c);      // k even
                float f1 = fmaf((float)((q >> (8 * jj + 4)) & 15u), s, c);  // k odd
                pk[jj] = pk2(f0, f1);
            }
            bv[i].x = pk[0]; bv[i].y = pk[1]; bv[i].z = pk[2]; bv[i].w = pk[3];
        }

        // regs -> LDS (fp16)
        uint4 av0, av1;
        av0.x = pk2(a0.x, a0.y); av0.y = pk2(a0.z, a0.w);
        av0.z = pk2(a1.x, a1.y); av0.w = pk2(a1.z, a1.w);
        av1.x = pk2(a2.x, a2.y); av1.y = pk2(a2.z, a2.w);
        av1.z = pk2(a3.x, a3.y); av1.w = pk2(a3.z, a3.w);
        *(uint4*)(al)          = av0;
        *(uint4*)(al + 8)      = av1;
        *(uint4*)(bs0)         = bv[0];   // k dkq*8 .. +8
        *(uint4*)(bs0 + 16)    = bv[1];   // k dkq*8+16 .. +8
        __syncthreads();

        // fragments + 16 MFMAs per wave
        f16x8 af[4], bfr[4];
        #pragma unroll
        for (int t = 0; t < 4; t++) {
            af[t]  = *(const f16x8*)(As + (wm + t * 16 + l15) * BKA + quad * 8);
            bfr[t] = *(const f16x8*)(Bs + (wn + t * 16 + l15) * BKP + quad * 8);
        }
        #pragma unroll
        for (int i = 0; i < 4; i++)
            #pragma unroll
            for (int j = 0; j < 4; j++)
                acc[i][j] = __builtin_amdgcn_mfma_f32_16x16x32_f16(af[i], bfr[j], acc[i][j], 0, 0, 0);
        __syncthreads();
    }

    // epilogue: C/D layout col=lane&15, row=quad*4+r  [m89/m91]; fp32 out
    #pragma unroll
    for (int i = 0; i < 4; i++) {
        const int mrow = m0 + wm + i * 16 + quad * 4;
        #pragma unroll
        for (int j = 0; j < 4; j++) {
            const int ncol = n0 + wn + j * 16 + l15;
            float* op = out + (size_t)mrow * N_DIM + ncol;
            #pragma unroll
            for (int r = 0; r < 4; r++)
                op[(size_t)r * N_DIM] = acc[i][j][r];
        }
    }
}

extern "C" void kernel_launch(void* const* d_in, const int* in_sizes, int n_in,
                              void* d_out, int out_size, void* d_ws, size_t ws_size,
                              hipStream_t stream) {
    const float* x  = (const float*)d_in[0];
    const int*   qw = (const int*)d_in[1];
    const float* sc = (const float*)d_in[2];
    const int*   qz = (const int*)d_in[3];
    // d_in[4] = g_idx, affine (k/128), not needed
    float* out = (float*)d_out;

    dim3 grid(N_DIM / BN, M_DIM / BM);  // (86, 32)
    gptq_gemm<<<grid, 256, 0, stream>>>(x, qw, sc, qz, out);
}

// Round 5
// 639.564 us; speedup vs baseline: 1.1259x; 1.1259x over previous
//
#include <hip/hip_runtime.h>

typedef unsigned short u16;
typedef unsigned int   u32;
typedef _Float16       f16;

#define M_DIM 4096
#define K_DIM 4096
#define N_DIM 11008
#define NQ8   (N_DIM / 8)
#define BM 128
#define BN 128
#define BK 32
#define BKP 40  // padded k-stride of Bs rows (halfs): 80B rows -> conflict-free frag reads

typedef f16   f16x8 __attribute__((ext_vector_type(8)));
typedef f16   f16x2 __attribute__((ext_vector_type(2)));
typedef float f32x4 __attribute__((ext_vector_type(4)));

typedef __attribute__((address_space(1))) void GV;
typedef __attribute__((address_space(3))) void LV;

__device__ __forceinline__ u32 pk2(float lo, float hi) {
    // v_cvt_pkrtz_f16_f32; exact for values that are fp16-representable (x is).
    return __builtin_bit_cast(u32, __builtin_amdgcn_cvt_pkrtz(lo, hi));
}

// x -> fp16 with per-8-group k-permutation: position pairs (k0,k4),(k1,k5),(k2,k6),(k3,k7).
// Matches the B-side nibble pairing (q>>4j gives nibbles j and j+4 in one mask).
__global__ __launch_bounds__(256) void cvt_x(const float* __restrict__ x, f16* __restrict__ xh) {
    const size_t t = (size_t)blockIdx.x * 256 + threadIdx.x;  // one 8-group per thread
    const float4* p = (const float4*)(x + t * 8);
    float4 a0 = p[0], a1 = p[1];
    uint4 v;
    v.x = pk2(a0.x, a1.x); v.y = pk2(a0.y, a1.y);
    v.z = pk2(a0.z, a1.z); v.w = pk2(a0.w, a1.w);
    *(uint4*)(xh + t * 8) = v;
}

// C = x[M,K] @ dequant(qweight)[K,N].  x,scales,out fp32 on device (fp16 promoted).
// W[k,n] = s[g,n] * (w - z - 1), g = k/128.  fp16 MFMA, fp32 accum.
// Dequant: ((q>>4j)&0x000F000F)|0x64006400 = fp16x2(1024+wj,1024+wj4) exact;
// pk_add exact integer bias -(1025+z); pk_mul by s = single fp16 rounding (= reference).
template<bool PRE>
__global__ __launch_bounds__(256, 2)
void gptq_gemm(const float* __restrict__ x, const f16* __restrict__ xh,
               const int* __restrict__ qw, const float* __restrict__ sc,
               const int* __restrict__ qz, float* __restrict__ out)
{
    constexpr int AK = PRE ? 32 : 40;  // unpadded when glds-staged (wave-uniform+lane*16 rule)
    __shared__ __align__(16) f16 As[BM * AK];
    __shared__ __align__(16) f16 Bs[BN * BKP];

    const int tid  = threadIdx.x;
    const int lane = tid & 63;
    const int wave = tid >> 6;
    const int quad = lane >> 4;
    const int l15  = lane & 15;
    const int wm   = (wave & 1) * 64;
    const int wn   = (wave >> 1) * 64;

    const int m0 = blockIdx.y * BM;
    const int n0 = blockIdx.x * BN;

    // --- A staging pointers ---
    // PRE: 2 x 16B glds per thread; LDS dest contiguous in tid order.
    const f16* agh0 = xh + (size_t)(m0 + (tid >> 2)) * K_DIM + (tid & 3) * 8;
    const f16* agh1 = agh0 + (size_t)64 * K_DIM;
    f16* al0 = As + tid * 8;
    f16* al1 = As + 2048 + tid * 8;
    // !PRE: fp32 load + inline cvt (with pairing permutation), padded rows.
    const float* agf = x + (size_t)(m0 + (tid >> 1)) * K_DIM + (tid & 1) * 16;
    f16* alf = As + (tid >> 1) * AK + (tid & 1) * 16;

    // --- B dequant params (fixed n per thread) ---
    const int dn  = tid & 127;
    const int dkq = tid >> 7;    // qweight rows dkq and dkq+2 of the k-tile
    const int gn  = n0 + dn;
    const int zsh = (gn & 7) * 4;
    const int*   qwp = qw + gn;
    const int*   qzp = qz + (gn >> 3);
    const float* scp = sc + gn;
    f16* bs0 = Bs + dn * BKP + dkq * 8;

    f32x4 acc[4][4];
    #pragma unroll
    for (int i = 0; i < 4; i++)
        #pragma unroll
        for (int j = 0; j < 4; j++)
            acc[i][j] = (f32x4){0.f, 0.f, 0.f, 0.f};

    for (int g = 0; g < K_DIM / 128; g++) {        // 32 quant groups
        const u32 zq = (u32)qzp[(size_t)g * NQ8];
        const int z1 = (int)((zq >> zsh) & 15u) + 1;
        const float s = scp[(size_t)g * N_DIM];
        const f16 sh = (f16)s;
        const f16 bh = (f16)(-(float)(1024 + z1));  // exact integer in fp16
        const f16x2 s2 = {sh, sh};
        const f16x2 b2 = {bh, bh};

        #pragma unroll
        for (int t = 0; t < 4; t++) {
            const int kt = g * 4 + t;

            if constexpr (PRE) {
                __builtin_amdgcn_global_load_lds((GV*)(agh0 + kt * BK), (LV*)al0, 16, 0, 0);
                __builtin_amdgcn_global_load_lds((GV*)(agh1 + kt * BK), (LV*)al1, 16, 0, 0);
            }

            // B: dequant 2 dwords (16 k-values) for this thread's n
            uint4 bv[2];
            #pragma unroll
            for (int i = 0; i < 2; i++) {
                const u32 q = (u32)qwp[(size_t)(4 * kt + dkq + 2 * i) * N_DIM];
                u32 pk[4];
                #pragma unroll
                for (int j = 0; j < 4; j++) {
                    const u32 mbits = ((q >> (4 * j)) & 0x000F000Fu) | 0x64006400u;
                    f16x2 v2 = __builtin_bit_cast(f16x2, mbits);
                    f16x2 w2 = (v2 + b2) * s2;      // v_pk_add_f16 (exact) + v_pk_mul_f16
                    pk[j] = __builtin_bit_cast(u32, w2);
                }
                bv[i].x = pk[0]; bv[i].y = pk[1]; bv[i].z = pk[2]; bv[i].w = pk[3];
            }

            if constexpr (!PRE) {
                const float4* agp = (const float4*)(agf + kt * BK);
                float4 a0 = agp[0], a1 = agp[1], a2 = agp[2], a3 = agp[3];
                uint4 av0, av1;  // pairing permutation: (k0,k4),(k1,k5),(k2,k6),(k3,k7)
                av0.x = pk2(a0.x, a1.x); av0.y = pk2(a0.y, a1.y);
                av0.z = pk2(a0.z, a1.z); av0.w = pk2(a0.w, a1.w);
                av1.x = pk2(a2.x, a3.x); av1.y = pk2(a2.y, a3.y);
                av1.z = pk2(a2.z, a3.z); av1.w = pk2(a2.w, a3.w);
                *(uint4*)(alf)     = av0;
                *(uint4*)(alf + 8) = av1;
            }
            *(uint4*)(bs0)      = bv[0];
            *(uint4*)(bs0 + 16) = bv[1];
            __syncthreads();

            f16x8 af[4], bfr[4];
            #pragma unroll
            for (int t2 = 0; t2 < 4; t2++) {
                af[t2]  = *(const f16x8*)(As + (wm + t2 * 16 + l15) * AK  + quad * 8);
                bfr[t2] = *(const f16x8*)(Bs + (wn + t2 * 16 + l15) * BKP + quad * 8);
            }
            #pragma unroll
            for (int i = 0; i < 4; i++)
                #pragma unroll
                for (int j = 0; j < 4; j++)
                    acc[i][j] = __builtin_amdgcn_mfma_f32_16x16x32_f16(af[i], bfr[j], acc[i][j], 0, 0, 0);
            __syncthreads();
        }
    }

    // epilogue: C/D layout col=lane&15, row=quad*4+r
    #pragma unroll
    for (int i = 0; i < 4; i++) {
        const int mrow = m0 + wm + i * 16 + quad * 4;
        #pragma unroll
        for (int j = 0; j < 4; j++) {
            const int ncol = n0 + wn + j * 16 + l15;
            float* op = out + (size_t)mrow * N_DIM + ncol;
            #pragma unroll
            for (int r = 0; r < 4; r++)
                op[(size_t)r * N_DIM] = acc[i][j][r];
        }
    }
}

extern "C" void kernel_launch(void* const* d_in, const int* in_sizes, int n_in,
                              void* d_out, int out_size, void* d_ws, size_t ws_size,
                              hipStream_t stream) {
    const float* x  = (const float*)d_in[0];
    const int*   qw = (const int*)d_in[1];
    const float* sc = (const float*)d_in[2];
    const int*   qz = (const int*)d_in[3];
    float* out = (float*)d_out;
    f16*   xh  = (f16*)d_ws;

    dim3 grid(N_DIM / BN, M_DIM / BM);  // (86, 32)
    const bool pre = ws_size >= (size_t)M_DIM * K_DIM * sizeof(f16);  // 32 MB
    if (pre) {
        cvt_x<<<(M_DIM * K_DIM / 8) / 256, 256, 0, stream>>>(x, xh);
        gptq_gemm<true><<<grid, 256, 0, stream>>>(x, xh, qw, sc, qz, out);
    } else {
        gptq_gemm<false><<<grid, 256, 0, stream>>>(x, xh, qw, sc, qz, out);
    }
}